// Round 12
// baseline (818.465 us; speedup 1.0000x reference)
//
#include <hip/hip_runtime.h>

// Disable implicit FP contraction: pairwise e^2/z^2 sums must round each
// product individually (numpy semantics). Explicit __fmaf_rn still fuses.
#pragma clang fp contract(off)

// VQ-VAE VectorQuantizer, two-tier:
//  Tier 1 (vq_gemm): plain-bf16 MFMA -> approx scores (err ~3e-5, same
//    order as np's own fp32 quantization). Float top-2 via min/median
//    (no u64 keys), codes ascending = np first-occurrence. Rows with
//    top-2 gap <= MARGIN get flags[row]=1. B staged to LDS dbuf, 64-code
//    chunks, 1 barrier/chunk.
//  Tier 2 (vq_rq): per-32-row block: inline EXACT np re-scan (R6-proven
//    sequential-k fp32 FMA + pairwise z2 + full-magnitude combine) of its
//    flagged rows, then gather-write quantized. Block 0 writes loss.
//  Loss: 1.25*(sum(z^2) [any-order, cvt] + sum(approx min score) [gemm])/N
//    -- error ~1e-5 abs, threshold is 2%.
// Out (f32): [0..16777215] quantized_st, [16777216] loss, [16777217..] idx.
// The q region doubles as scratch for bf16 z (zah) until vq_rq rewrites it.

#define NROWS   65536
#define DDIM    256
#define KCODES  1024
#define QSIZE   (NROWS * DDIM)
#define LOSS_OFF QSIZE
#define IDX_OFF (QSIZE + 1)
#define MARGIN  3.0e-4f

typedef __bf16 bf16x8 __attribute__((ext_vector_type(8)));
typedef float f32x4 __attribute__((ext_vector_type(4)));
typedef unsigned int u32;
typedef unsigned long long u64;
typedef unsigned short u16;
typedef unsigned char u8;

#define GLOAD_LDS16(gsrc, ldst) \
    __builtin_amdgcn_global_load_lds( \
        (const __attribute__((address_space(1))) u32*)(gsrc), \
        (__attribute__((address_space(3))) u32*)(ldst), 16, 0, 0)

__device__ __forceinline__ u32 omap(float s) {
    u32 u = __float_as_uint(s);
    return (u & 0x80000000u) ? ~u : (u | 0x80000000u);
}
__device__ __forceinline__ u64 pack_key(float s, u32 j) {
    return ((u64)omap(s) << 32) | j;
}

// numpy pairwise sum-of-squares over 128 floats (unrolled-8 path)
__device__ __forceinline__ float pw128_sq(const float* __restrict__ x) {
    float r[8];
    #pragma unroll
    for (int j = 0; j < 8; ++j) r[j] = x[j] * x[j];
    for (int i = 8; i < 128; i += 8)
        #pragma unroll
        for (int j = 0; j < 8; ++j) r[j] += x[i + j] * x[i + j];
    return ((r[0] + r[1]) + (r[2] + r[3])) + ((r[4] + r[5]) + (r[6] + r[7]));
}

// ---- codebook prep: ebh bf16 [ksub(32)][code(1024)][8], np-e2, zero sum ----
__global__ __launch_bounds__(256) void vq_pack_cb(
    const float* __restrict__ E, u16* __restrict__ ebh,
    float* __restrict__ ee, float* __restrict__ sum) {
    int j = blockIdx.x * 256 + threadIdx.x;
    if (j == 0) *sum = 0.0f;
    if (j >= KCODES) return;
    const float* row = E + (size_t)j * DDIM;
    #pragma unroll
    for (int ks = 0; ks < 32; ++ks) {
        bf16x8 h8;
        #pragma unroll
        for (int e = 0; e < 8; ++e) h8[e] = (__bf16)row[ks * 8 + e];
        *(bf16x8*)(ebh + ((size_t)ks * KCODES + j) * 8) = h8;
    }
    ee[j] = pw128_sq(row) + pw128_sq(row + 128);
}

// ---- z prep: zah bf16 [ksub(32)][row(65536)][8] into q region; Sum z^2 ----
__global__ __launch_bounds__(256) void vq_cvt(
    const float* __restrict__ Z, u16* zah, float* __restrict__ sum) {
    __shared__ float zs[32 * 256];
    const int t = threadIdx.x;
    const size_t rowbase = (size_t)blockIdx.x * 32;
    const float4* Zt = (const float4*)(Z + rowbase * DDIM);
    float ss = 0.0f;
    #pragma unroll
    for (int k = 0; k < 8; ++k) {
        float4 v = Zt[t + 256 * k];
        ((float4*)zs)[t + 256 * k] = v;
        ss += v.x * v.x + v.y * v.y + v.z * v.z + v.w * v.w;
    }
    // wave-reduce ss, one atomic per wave (loss term; any order OK)
    #pragma unroll
    for (int off = 1; off < 64; off <<= 1) ss += __shfl_xor(ss, off);
    if ((t & 63) == 0) atomicAdd(sum, ss);
    __syncthreads();
    // bf16 convert, k-major pieces: p = t + 256*i -> row=p&31, ksub=p>>5
    #pragma unroll
    for (int i = 0; i < 4; ++i) {
        int p = t + 256 * i;
        int row = p & 31, ks = p >> 5;
        bf16x8 h8;
        #pragma unroll
        for (int e = 0; e < 8; ++e) h8[e] = (__bf16)zs[row * 256 + ks * 8 + e];
        *(bf16x8*)(zah + ((size_t)ks * NROWS + rowbase + row) * 8) = h8;
    }
}

// ---- tier-1 MFMA GEMM: LDS dbuf 64-code chunks, float top-2 fused ----
__device__ __forceinline__ void stage_chunk(
    const u16* __restrict__ ebh, int chbase, char* buf, int t) {
    // 64 codes x 32 ksubs x 16B; lane-linear LDS (p*16)
    #pragma unroll
    for (int i = 0; i < 8; ++i) {
        int p = t + 256 * i;
        int ks = p >> 6, c = p & 63;
        GLOAD_LDS16(ebh + ((size_t)ks * KCODES + chbase + c) * 8, buf + p * 16);
    }
}

__global__ __launch_bounds__(256, 2) void vq_gemm(
    const u16* zah,
    const u16* __restrict__ ebh,
    const float* __restrict__ ee,
    float* out, float* __restrict__ sum, u8* __restrict__ flags) {
    __shared__ __align__(16) char bs[2][32768];   // double-buffered B chunk
    const int t = threadIdx.x, w = t >> 6, l = t & 63;
    const int lr = l & 15, lg = l >> 4;
    const int rowbase = blockIdx.x * 128;

    // A fragments in registers: [rowfrag][kstep]
    bf16x8 aH[2][8];
    #pragma unroll
    for (int rf = 0; rf < 2; ++rf)
        #pragma unroll
        for (int s = 0; s < 8; ++s) {
            size_t off = ((size_t)(s * 4 + lg) * NROWS + rowbase + w * 32 + rf * 16 + lr) * 8;
            aH[rf][s] = *(const bf16x8*)(zah + off);
        }

    float s1[2][4], s2[2][4]; int i1[2][4];
    #pragma unroll
    for (int rf = 0; rf < 2; ++rf)
        #pragma unroll
        for (int r = 0; r < 4; ++r) { s1[rf][r] = 1e30f; s2[rf][r] = 1e30f; i1[rf][r] = 0x7FFFFFFF; }

    int cur = 0;
    stage_chunk(ebh, 0, bs[0], t);
    for (int ch = 0; ch < 16; ++ch) {
        __syncthreads();                    // drains this chunk's gload_lds
        if (ch + 1 < 16) stage_chunk(ebh, (ch + 1) * 64, bs[cur ^ 1], t);
        const char* buf = bs[cur];
        const int chbase = ch * 64;

        f32x4 acc[2][4];
        #pragma unroll
        for (int rf = 0; rf < 2; ++rf)
            #pragma unroll
            for (int cf = 0; cf < 4; ++cf) acc[rf][cf] = 0.0f;

        #pragma unroll
        for (int s = 0; s < 8; ++s) {
            #pragma unroll
            for (int cf = 0; cf < 4; ++cf) {
                int off = (((s * 4 + lg) * 64 + cf * 16 + lr) * 16);
                bf16x8 bh = *(const bf16x8*)(buf + off);
                #pragma unroll
                for (int rf = 0; rf < 2; ++rf)
                    acc[rf][cf] = __builtin_amdgcn_mfma_f32_16x16x32_bf16(aH[rf][s], bh, acc[rf][cf], 0, 0, 0);
            }
        }
        // epilogue: float top-2 (s2 via min/max median trick), codes ascending
        #pragma unroll
        for (int cf = 0; cf < 4; ++cf) {
            int code = chbase + cf * 16 + lr;
            float e2c = ee[code];
            #pragma unroll
            for (int rf = 0; rf < 2; ++rf)
                #pragma unroll
                for (int r = 0; r < 4; ++r) {
                    float v = __fmaf_rn(-2.0f, acc[rf][cf][r], e2c);
                    float so = s1[rf][r];
                    s2[rf][r] = fminf(fmaxf(so, v), s2[rf][r]);  // median(so,s2,v)
                    bool lt = v < so;
                    s1[rf][r] = lt ? v : so;
                    i1[rf][r] = lt ? code : i1[rf][r];
                }
        }
        cur ^= 1;
    }
    // butterfly across the 16 lanes of each row group (lr bits only)
    #pragma unroll
    for (int off = 1; off < 16; off <<= 1) {
        #pragma unroll
        for (int rf = 0; rf < 2; ++rf)
            #pragma unroll
            for (int r = 0; r < 4; ++r) {
                float os1 = __shfl_xor(s1[rf][r], off);
                float os2 = __shfl_xor(s2[rf][r], off);
                int   oi  = __shfl_xor(i1[rf][r], off);
                float ns2 = fminf(fmaxf(s1[rf][r], os1), fminf(s2[rf][r], os2));
                bool take = (os1 < s1[rf][r]) || (os1 == s1[rf][r] && oi < i1[rf][r]);
                s1[rf][r] = take ? os1 : s1[rf][r];
                i1[rf][r] = take ? oi : i1[rf][r];
                s2[rf][r] = ns2;
            }
    }
    if (lr == 0) {
        float lsum = 0.0f;
        #pragma unroll
        for (int rf = 0; rf < 2; ++rf)
            #pragma unroll
            for (int r = 0; r < 4; ++r) {
                int row = rowbase + w * 32 + rf * 16 + lg * 4 + r;
                out[(size_t)IDX_OFF + row] = (float)i1[rf][r];
                flags[row] = (s2[rf][r] <= s1[rf][r] + MARGIN) ? 1 : 0;
                lsum += s1[rf][r];
            }
        atomicAdd(sum, lsum);
    }
}

// ---- tier-2: per-32-row block: exact np rescue of flagged rows (R6
//      arithmetic), then gather-write quantized. Block 0 writes loss. ----
__global__ __launch_bounds__(256) void vq_rq(
    const float* __restrict__ Z, const float* __restrict__ E,
    const float* __restrict__ ee, const u8* __restrict__ flags,
    const float* __restrict__ sum, float* out) {
    __shared__ float zrow[DDIM];
    __shared__ float za[16];
    __shared__ float zs2s;
    __shared__ u64 rmin;
    __shared__ int fl_rows[32];
    __shared__ int nfl;
    __shared__ int qidx[32];
    const int t = threadIdx.x;
    const size_t rowbase = (size_t)blockIdx.x * 32;

    if (blockIdx.x == 0 && t == 0) out[LOSS_OFF] = 1.25f * (*sum) / (float)QSIZE;

    if (t == 0) nfl = 0;
    __syncthreads();
    if (t < 32 && flags[rowbase + t]) { int s = atomicAdd(&nfl, 1); fl_rows[s] = t; }
    __syncthreads();

    for (int i = 0; i < nfl; ++i) {
        int row = (int)rowbase + fl_rows[i];
        if (t < 64) ((float4*)zrow)[t] = ((const float4*)(Z + (size_t)row * DDIM))[t];
        if (t == 0) rmin = ~0ULL;
        __syncthreads();
        if (t < 8) {   // np pairwise z2
            int j = t;
            float a0 = zrow[j] * zrow[j], a1 = zrow[128 + j] * zrow[128 + j];
            for (int k = 8; k < 128; k += 8) {
                a0 += zrow[k + j] * zrow[k + j];
                a1 += zrow[128 + k + j] * zrow[128 + k + j];
            }
            za[j] = a0; za[8 + j] = a1;
        }
        __syncthreads();
        if (t == 0) {
            float c0 = ((za[0] + za[1]) + (za[2] + za[3])) + ((za[4] + za[5]) + (za[6] + za[7]));
            float c1 = ((za[8] + za[9]) + (za[10] + za[11])) + ((za[12] + za[13]) + (za[14] + za[15]));
            zs2s = c0 + c1;
        }
        __syncthreads();
        float zr2 = zs2s;
        u64 best = ~0ULL;
        #pragma unroll
        for (int c = 0; c < 4; ++c) {
            int code = t + c * 256;
            const float4* er = (const float4*)(E + (size_t)code * DDIM);
            float a = 0.0f;
            for (int d4 = 0; d4 < 64; ++d4) {   // sequential-k fp32 FMA chain
                float4 ev = er[d4];
                float4 zv = ((const float4*)zrow)[d4];
                a = __fmaf_rn(zv.x, ev.x, a); a = __fmaf_rn(zv.y, ev.y, a);
                a = __fmaf_rn(zv.z, ev.z, a); a = __fmaf_rn(zv.w, ev.w, a);
            }
            float d = (zr2 + ee[code]) - 2.0f * a;   // np full-magnitude combine
            u64 k = pack_key(d, (u32)code);
            if (k < best) best = k;
        }
        #pragma unroll
        for (int off = 1; off < 64; off <<= 1) {
            u64 o = __shfl_xor(best, off);
            if (o < best) best = o;
        }
        if ((t & 63) == 0) atomicMin(&rmin, best);
        __syncthreads();
        if (t == 0) out[(size_t)IDX_OFF + row] = (float)(u32)(rmin & 0xFFFFFFFFu);
        __syncthreads();
    }

    // gather-write quantized for all 32 rows (indices now final)
    if (t < 32) qidx[t] = (int)out[(size_t)IDX_OFF + rowbase + t];
    __syncthreads();
    float4* outq = (float4*)out;
    #pragma unroll
    for (int k = 0; k < 8; ++k) {
        int idx = t + 256 * k;
        int r = idx >> 6, c4 = idx & 63;
        int code = qidx[r];
        outq[rowbase * 64 + idx] = ((const float4*)(E + (size_t)code * DDIM))[c4];
    }
}

extern "C" void kernel_launch(void* const* d_in, const int* in_sizes, int n_in,
                              void* d_out, int out_size, void* d_ws, size_t ws_size,
                              hipStream_t stream) {
    const float* Z; const float* E;
    if (in_sizes[0] == QSIZE) { Z = (const float*)d_in[0]; E = (const float*)d_in[1]; }
    else                      { Z = (const float*)d_in[1]; E = (const float*)d_in[0]; }
    float* out = (float*)d_out;
    char* ws = (char*)d_ws;

    float* sum   = (float*)ws;                      // @0
    float* ee    = (float*)(ws + 1024);             // 4 KB
    u16*   ebh   = (u16*)(ws + 8192);               // 512 KB
    u8*    flags = (u8*)(ws + 8192 + 524288);       // 64 KB (total ~0.6 MB)

    // bf16 z scratch lives in the q-output region until vq_rq rewrites it
    u16* zah = (u16*)out;

    vq_pack_cb<<<4, 256, 0, stream>>>(E, ebh, ee, sum);
    vq_cvt<<<NROWS / 32, 256, 0, stream>>>(Z, zah, sum);
    vq_gemm<<<NROWS / 128, 256, 0, stream>>>(zah, ebh, ee, out, sum, flags);
    vq_rq<<<NROWS / 32, 256, 0, stream>>>(Z, E, ee, flags, sum, out);
}

// Round 13
// 339.596 us; speedup vs baseline: 2.4101x; 2.4101x over previous
//
#include <hip/hip_runtime.h>

// Disable implicit FP contraction: pairwise e^2/z^2 sums must round each
// product individually (numpy semantics). Explicit __fmaf_rn still fuses.
#pragma clang fp contract(off)

// VQ-VAE VectorQuantizer, two-tier:
//  Tier 1 (vq_gemm): plain-bf16 MFMA -> approx scores (err ~3e-5, same
//    order as np's own fp32 quantization). Float top-2 via min/median,
//    codes ascending = np first-occurrence. Rows with top-2 gap <= MARGIN
//    appended to list. B staged to LDS dbuf, 64-code chunks, 1 barrier/chunk.
//  Tier 2 (vq_rescue): EXACT np re-scan (R6-proven sequential-k fp32 FMA +
//    pairwise z2 + full-magnitude combine), BATCHED 16 rows/block (R8/R12
//    lesson: unbatched rescue re-reads the 1MB codebook per row -> 675us).
//  Loss: 1.25*(sum(z^2) [any-order, cvt] + sum(approx min score) [gemm])/N.
// Out (f32): [0..16777215] quantized_st, [16777216] loss, [16777217..] idx.
// The q region doubles as scratch for bf16 z (zah) until vq_qwrite.

#define NROWS   65536
#define DDIM    256
#define KCODES  1024
#define QSIZE   (NROWS * DDIM)
#define LOSS_OFF QSIZE
#define IDX_OFF (QSIZE + 1)
#define MARGIN  3.0e-4f
#define RCAP    16384
#define RBATCH  16

typedef __bf16 bf16x8 __attribute__((ext_vector_type(8)));
typedef float f32x4 __attribute__((ext_vector_type(4)));
typedef unsigned int u32;
typedef unsigned long long u64;
typedef unsigned short u16;

#define GLOAD_LDS16(gsrc, ldst) \
    __builtin_amdgcn_global_load_lds( \
        (const __attribute__((address_space(1))) u32*)(gsrc), \
        (__attribute__((address_space(3))) u32*)(ldst), 16, 0, 0)

__device__ __forceinline__ u32 omap(float s) {
    u32 u = __float_as_uint(s);
    return (u & 0x80000000u) ? ~u : (u | 0x80000000u);
}
__device__ __forceinline__ u64 pack_key(float s, u32 j) {
    return ((u64)omap(s) << 32) | j;
}

// numpy pairwise sum-of-squares over 128 floats (unrolled-8 path)
__device__ __forceinline__ float pw128_sq(const float* __restrict__ x) {
    float r[8];
    #pragma unroll
    for (int j = 0; j < 8; ++j) r[j] = x[j] * x[j];
    for (int i = 8; i < 128; i += 8)
        #pragma unroll
        for (int j = 0; j < 8; ++j) r[j] += x[i + j] * x[i + j];
    return ((r[0] + r[1]) + (r[2] + r[3])) + ((r[4] + r[5]) + (r[6] + r[7]));
}

// ---- codebook prep: ebh bf16 [ksub(32)][code(1024)][8], np-e2 ----
__global__ __launch_bounds__(256) void vq_pack_cb(
    const float* __restrict__ E, u16* __restrict__ ebh,
    float* __restrict__ ee, float* __restrict__ sum, int* __restrict__ count) {
    int j = blockIdx.x * 256 + threadIdx.x;
    if (j == 0) { *sum = 0.0f; *count = 0; }
    if (j >= KCODES) return;
    const float* row = E + (size_t)j * DDIM;
    #pragma unroll
    for (int ks = 0; ks < 32; ++ks) {
        bf16x8 h8;
        #pragma unroll
        for (int e = 0; e < 8; ++e) h8[e] = (__bf16)row[ks * 8 + e];
        *(bf16x8*)(ebh + ((size_t)ks * KCODES + j) * 8) = h8;
    }
    ee[j] = pw128_sq(row) + pw128_sq(row + 128);
}

// ---- z prep: zah bf16 [ksub(32)][row(65536)][8] into q region; Sum z^2 ----
__global__ __launch_bounds__(256) void vq_cvt(
    const float* __restrict__ Z, u16* zah, float* __restrict__ sum) {
    __shared__ float zs[32 * 256];
    const int t = threadIdx.x;
    const size_t rowbase = (size_t)blockIdx.x * 32;
    const float4* Zt = (const float4*)(Z + rowbase * DDIM);
    float ss = 0.0f;
    #pragma unroll
    for (int k = 0; k < 8; ++k) {
        float4 v = Zt[t + 256 * k];
        ((float4*)zs)[t + 256 * k] = v;
        ss += v.x * v.x + v.y * v.y + v.z * v.z + v.w * v.w;
    }
    #pragma unroll
    for (int off = 1; off < 64; off <<= 1) ss += __shfl_xor(ss, off);
    if ((t & 63) == 0) atomicAdd(sum, ss);
    __syncthreads();
    // bf16 convert, k-major pieces: p = t + 256*i -> row=p&31, ksub=p>>5
    #pragma unroll
    for (int i = 0; i < 4; ++i) {
        int p = t + 256 * i;
        int row = p & 31, ks = p >> 5;
        bf16x8 h8;
        #pragma unroll
        for (int e = 0; e < 8; ++e) h8[e] = (__bf16)zs[row * 256 + ks * 8 + e];
        *(bf16x8*)(zah + ((size_t)ks * NROWS + rowbase + row) * 8) = h8;
    }
}

// ---- tier-1 MFMA GEMM: LDS dbuf 64-code chunks, float top-2 fused ----
__device__ __forceinline__ void stage_chunk(
    const u16* __restrict__ ebh, int chbase, char* buf, int t) {
    // 64 codes x 32 ksubs x 16B; lane-linear LDS (p*16)
    #pragma unroll
    for (int i = 0; i < 8; ++i) {
        int p = t + 256 * i;
        int ks = p >> 6, c = p & 63;
        GLOAD_LDS16(ebh + ((size_t)ks * KCODES + chbase + c) * 8, buf + p * 16);
    }
}

__global__ __launch_bounds__(256, 2) void vq_gemm(
    const u16* zah,
    const u16* __restrict__ ebh,
    const float* __restrict__ ee,
    float* out, float* __restrict__ sum, int* __restrict__ count,
    int* __restrict__ list) {
    __shared__ __align__(16) char bs[2][32768];   // double-buffered B chunk
    const int t = threadIdx.x, w = t >> 6, l = t & 63;
    const int lr = l & 15, lg = l >> 4;
    const int rowbase = blockIdx.x * 128;

    // A fragments in registers: [rowfrag][kstep]
    bf16x8 aH[2][8];
    #pragma unroll
    for (int rf = 0; rf < 2; ++rf)
        #pragma unroll
        for (int s = 0; s < 8; ++s) {
            size_t off = ((size_t)(s * 4 + lg) * NROWS + rowbase + w * 32 + rf * 16 + lr) * 8;
            aH[rf][s] = *(const bf16x8*)(zah + off);
        }

    float s1[2][4], s2[2][4]; int i1[2][4];
    #pragma unroll
    for (int rf = 0; rf < 2; ++rf)
        #pragma unroll
        for (int r = 0; r < 4; ++r) { s1[rf][r] = 1e30f; s2[rf][r] = 1e30f; i1[rf][r] = 0x7FFFFFFF; }

    int cur = 0;
    stage_chunk(ebh, 0, bs[0], t);
    for (int ch = 0; ch < 16; ++ch) {
        __syncthreads();                    // drains this chunk's gload_lds
        if (ch + 1 < 16) stage_chunk(ebh, (ch + 1) * 64, bs[cur ^ 1], t);
        const char* buf = bs[cur];
        const int chbase = ch * 64;

        f32x4 acc[2][4];
        #pragma unroll
        for (int rf = 0; rf < 2; ++rf)
            #pragma unroll
            for (int cf = 0; cf < 4; ++cf) acc[rf][cf] = 0.0f;

        #pragma unroll
        for (int s = 0; s < 8; ++s) {
            #pragma unroll
            for (int cf = 0; cf < 4; ++cf) {
                int off = (((s * 4 + lg) * 64 + cf * 16 + lr) * 16);
                bf16x8 bh = *(const bf16x8*)(buf + off);
                #pragma unroll
                for (int rf = 0; rf < 2; ++rf)
                    acc[rf][cf] = __builtin_amdgcn_mfma_f32_16x16x32_bf16(aH[rf][s], bh, acc[rf][cf], 0, 0, 0);
            }
        }
        // epilogue: float top-2 (s2 via min/max median trick), codes ascending
        #pragma unroll
        for (int cf = 0; cf < 4; ++cf) {
            int code = chbase + cf * 16 + lr;
            float e2c = ee[code];
            #pragma unroll
            for (int rf = 0; rf < 2; ++rf)
                #pragma unroll
                for (int r = 0; r < 4; ++r) {
                    float v = __fmaf_rn(-2.0f, acc[rf][cf][r], e2c);
                    float so = s1[rf][r];
                    s2[rf][r] = fminf(fmaxf(so, v), s2[rf][r]);  // median(so,s2,v)
                    bool lt = v < so;
                    s1[rf][r] = lt ? v : so;
                    i1[rf][r] = lt ? code : i1[rf][r];
                }
        }
        cur ^= 1;
    }
    // butterfly across the 16 lanes of each row group (lr bits only)
    #pragma unroll
    for (int off = 1; off < 16; off <<= 1) {
        #pragma unroll
        for (int rf = 0; rf < 2; ++rf)
            #pragma unroll
            for (int r = 0; r < 4; ++r) {
                float os1 = __shfl_xor(s1[rf][r], off);
                float os2 = __shfl_xor(s2[rf][r], off);
                int   oi  = __shfl_xor(i1[rf][r], off);
                float ns2 = fminf(fmaxf(s1[rf][r], os1), fminf(s2[rf][r], os2));
                bool take = (os1 < s1[rf][r]) || (os1 == s1[rf][r] && oi < i1[rf][r]);
                s1[rf][r] = take ? os1 : s1[rf][r];
                i1[rf][r] = take ? oi : i1[rf][r];
                s2[rf][r] = ns2;
            }
    }
    if (lr == 0) {
        float lsum = 0.0f;
        #pragma unroll
        for (int rf = 0; rf < 2; ++rf)
            #pragma unroll
            for (int r = 0; r < 4; ++r) {
                int row = rowbase + w * 32 + rf * 16 + lg * 4 + r;
                out[(size_t)IDX_OFF + row] = (float)i1[rf][r];
                lsum += s1[rf][r];
                if (s2[rf][r] <= s1[rf][r] + MARGIN) {
                    int slot = atomicAdd(count, 1);
                    if (slot < RCAP) list[slot] = row;
                }
            }
        atomicAdd(sum, lsum);
    }
}

// ---- tier-2 exact np re-scan, BATCHED 16 rows/block (R6/R8 arithmetic) ----
__global__ __launch_bounds__(256) void vq_rescue(
    const float* __restrict__ Z, const float* __restrict__ E,
    const float* __restrict__ ee, const int* __restrict__ count,
    const int* __restrict__ list, float* out) {
    __shared__ float zrow[RBATCH][DDIM];    // 16 KB
    __shared__ float zacc[RBATCH][16];
    __shared__ float z2s[RBATCH];
    __shared__ u64 rmin[RBATCH];
    __shared__ int rowid[RBATCH];
    int n = *count; if (n > RCAP) n = RCAP;
    const int t = threadIdx.x;
    const int base = blockIdx.x * RBATCH;
    if (base >= n) return;
    int nb = n - base; if (nb > RBATCH) nb = RBATCH;

    if (t < RBATCH) {
        rowid[t] = (t < nb) ? list[base + t] : 0;
        rmin[t] = ~0ULL;
    }
    __syncthreads();
    // stage z rows (coalesced float4): 16 rows x 64 float4
    #pragma unroll
    for (int i = 0; i < RBATCH * (DDIM / 4) / 256; ++i) {
        int p = t + 256 * i;
        int r = p >> 6, c4 = p & 63;
        if (r < nb) ((float4*)zrow[r])[c4] =
            ((const float4*)(Z + (size_t)rowid[r] * DDIM))[c4];
    }
    __syncthreads();
    // np pairwise z2 per row
    if (t < RBATCH * 8) {
        int r = t >> 3, j = t & 7;
        const float* zr = zrow[r];
        float a0 = zr[j] * zr[j], a1 = zr[128 + j] * zr[128 + j];
        for (int i = 8; i < 128; i += 8) {
            a0 += zr[i + j] * zr[i + j];
            a1 += zr[128 + i + j] * zr[128 + i + j];
        }
        zacc[r][j] = a0; zacc[r][8 + j] = a1;
    }
    __syncthreads();
    if (t < RBATCH) {
        const float* a = zacc[t];
        float c0 = ((a[0] + a[1]) + (a[2] + a[3])) + ((a[4] + a[5]) + (a[6] + a[7]));
        float c1 = ((a[8] + a[9]) + (a[10] + a[11])) + ((a[12] + a[13]) + (a[14] + a[15]));
        z2s[t] = c0 + c1;
    }
    __syncthreads();

    // dots: thread t owns codes {t,+256,+512,+768} x all RBATCH rows;
    // strict sequential fp32 FMA chain over k ascending per (row,code).
    float acc[4][RBATCH];
    #pragma unroll
    for (int c = 0; c < 4; ++c)
        #pragma unroll
        for (int r = 0; r < RBATCH; ++r) acc[c][r] = 0.0f;

    for (int d4 = 0; d4 < DDIM / 4; ++d4) {
        float4 ev[4];
        #pragma unroll
        for (int c = 0; c < 4; ++c)
            ev[c] = ((const float4*)(E + (size_t)(t + c * 256) * DDIM))[d4];
        #pragma unroll
        for (int r = 0; r < RBATCH; ++r) {
            float4 zv = ((const float4*)zrow[r])[d4];
            #pragma unroll
            for (int c = 0; c < 4; ++c) {
                float a = acc[c][r];
                a = __fmaf_rn(zv.x, ev[c].x, a); a = __fmaf_rn(zv.y, ev[c].y, a);
                a = __fmaf_rn(zv.z, ev[c].z, a); a = __fmaf_rn(zv.w, ev[c].w, a);
                acc[c][r] = a;
            }
        }
    }
    // per-row argmin: np full-magnitude combine + first-min tie-break
    float e2c[4];
    #pragma unroll
    for (int c = 0; c < 4; ++c) e2c[c] = ee[t + c * 256];
    #pragma unroll
    for (int r = 0; r < RBATCH; ++r) {
        float zr2 = z2s[r];
        u64 best = ~0ULL;
        #pragma unroll
        for (int c = 0; c < 4; ++c) {
            float d = (zr2 + e2c[c]) - 2.0f * acc[c][r];
            u64 k = pack_key(d, (u32)(t + c * 256));
            if (k < best) best = k;
        }
        #pragma unroll
        for (int off = 1; off < 64; off <<= 1) {
            u64 o = __shfl_xor(best, off);
            if (o < best) best = o;
        }
        if ((t & 63) == 0) atomicMin(&rmin[r], best);
    }
    __syncthreads();
    if (t < nb) out[(size_t)IDX_OFF + rowid[t]] = (float)(u32)(rmin[t] & 0xFFFFFFFFu);
}

// ---- gather codebook rows into quantized output; block 0 writes loss ----
__global__ __launch_bounds__(256) void vq_qwrite(
    const float* __restrict__ E, const float* __restrict__ sum, float* out) {
    __shared__ int qidx[32];
    const int t = threadIdx.x;
    const size_t rowbase = (size_t)blockIdx.x * 32;
    if (blockIdx.x == 0 && t == 0) out[LOSS_OFF] = 1.25f * (*sum) / (float)QSIZE;
    if (t < 32) qidx[t] = (int)out[(size_t)IDX_OFF + rowbase + t];
    __syncthreads();
    float4* outq = (float4*)out;
    #pragma unroll
    for (int k = 0; k < 8; ++k) {
        int idx = t + 256 * k;
        int r = idx >> 6, c4 = idx & 63;
        int code = qidx[r];
        outq[rowbase * 64 + idx] = ((const float4*)(E + (size_t)code * DDIM))[c4];
    }
}

extern "C" void kernel_launch(void* const* d_in, const int* in_sizes, int n_in,
                              void* d_out, int out_size, void* d_ws, size_t ws_size,
                              hipStream_t stream) {
    const float* Z; const float* E;
    if (in_sizes[0] == QSIZE) { Z = (const float*)d_in[0]; E = (const float*)d_in[1]; }
    else                      { Z = (const float*)d_in[1]; E = (const float*)d_in[0]; }
    float* out = (float*)d_out;
    char* ws = (char*)d_ws;

    float* sum   = (float*)ws;                      // @0
    int*   count = (int*)(ws + 4);                  // @4
    float* ee    = (float*)(ws + 1024);             // 4 KB
    u16*   ebh   = (u16*)(ws + 8192);               // 512 KB
    int*   list  = (int*)(ws + 8192 + 524288);      // 64 KB (total ~0.6 MB)

    // bf16 z scratch lives in the q-output region until vq_qwrite
    u16* zah = (u16*)out;

    vq_pack_cb<<<4, 256, 0, stream>>>(E, ebh, ee, sum, count);
    vq_cvt<<<NROWS / 32, 256, 0, stream>>>(Z, zah, sum);
    vq_gemm<<<NROWS / 128, 256, 0, stream>>>(zah, ebh, ee, out, sum, count, list);
    vq_rescue<<<RCAP / RBATCH, 256, 0, stream>>>(Z, E, ee, count, list, out);
    vq_qwrite<<<NROWS / 32, 256, 0, stream>>>(E, sum, out);
}

// Round 14
// 335.883 us; speedup vs baseline: 2.4368x; 1.0111x over previous
//
#include <hip/hip_runtime.h>

// Disable implicit FP contraction: pairwise e^2/z^2 sums must round each
// product individually (numpy semantics). Explicit __fmaf_rn still fuses.
#pragma clang fp contract(off)

// VQ-VAE VectorQuantizer, two-tier:
//  Tier 1 (vq_gemm): plain-bf16 MFMA -> approx scores (err ~3e-5, same
//    order as np's own fp32 quantization). Float top-2 via min/median,
//    codes ascending = np first-occurrence. Rows with top-2 gap <= MARGIN
//    appended to list. B staged to LDS dbuf, 64-code chunks, 1 barrier/chunk.
//  Tier 2 (vq_rescue): EXACT np re-scan (R6-proven sequential-k fp32 FMA +
//    pairwise z2 + full-magnitude combine), BATCHED 16 rows/block.
//  vq_cvt (R13 fix): NO LDS -- each piece zah[ks][row][8] is two consecutive
//    float4s of Z[row]; direct gather, wave-level 64B line pairing, 0 bank
//    conflicts (old LDS transpose was a 32-way conflict, 113us).
//  Loss: 1.25*(sum(z^2) [any-order, cvt] + sum(approx min score) [gemm])/N.
// Out (f32): [0..16777215] quantized_st, [16777216] loss, [16777217..] idx.
// The q region doubles as scratch for bf16 z (zah) until vq_qwrite.

#define NROWS   65536
#define DDIM    256
#define KCODES  1024
#define QSIZE   (NROWS * DDIM)
#define LOSS_OFF QSIZE
#define IDX_OFF (QSIZE + 1)
#define MARGIN  3.0e-4f
#define RCAP    16384
#define RBATCH  16

typedef __bf16 bf16x8 __attribute__((ext_vector_type(8)));
typedef float f32x4 __attribute__((ext_vector_type(4)));
typedef unsigned int u32;
typedef unsigned long long u64;
typedef unsigned short u16;

#define GLOAD_LDS16(gsrc, ldst) \
    __builtin_amdgcn_global_load_lds( \
        (const __attribute__((address_space(1))) u32*)(gsrc), \
        (__attribute__((address_space(3))) u32*)(ldst), 16, 0, 0)

__device__ __forceinline__ u32 omap(float s) {
    u32 u = __float_as_uint(s);
    return (u & 0x80000000u) ? ~u : (u | 0x80000000u);
}
__device__ __forceinline__ u64 pack_key(float s, u32 j) {
    return ((u64)omap(s) << 32) | j;
}

// numpy pairwise sum-of-squares over 128 floats (unrolled-8 path)
__device__ __forceinline__ float pw128_sq(const float* __restrict__ x) {
    float r[8];
    #pragma unroll
    for (int j = 0; j < 8; ++j) r[j] = x[j] * x[j];
    for (int i = 8; i < 128; i += 8)
        #pragma unroll
        for (int j = 0; j < 8; ++j) r[j] += x[i + j] * x[i + j];
    return ((r[0] + r[1]) + (r[2] + r[3])) + ((r[4] + r[5]) + (r[6] + r[7]));
}

// ---- codebook prep: ebh bf16 [ksub(32)][code(1024)][8], np-e2 ----
__global__ __launch_bounds__(256) void vq_pack_cb(
    const float* __restrict__ E, u16* __restrict__ ebh,
    float* __restrict__ ee, float* __restrict__ sum, int* __restrict__ count) {
    int j = blockIdx.x * 256 + threadIdx.x;
    if (j == 0) { *sum = 0.0f; *count = 0; }
    if (j >= KCODES) return;
    const float* row = E + (size_t)j * DDIM;
    #pragma unroll
    for (int ks = 0; ks < 32; ++ks) {
        bf16x8 h8;
        #pragma unroll
        for (int e = 0; e < 8; ++e) h8[e] = (__bf16)row[ks * 8 + e];
        *(bf16x8*)(ebh + ((size_t)ks * KCODES + j) * 8) = h8;
    }
    ee[j] = pw128_sq(row) + pw128_sq(row + 128);
}

// ---- z prep: zah bf16 [ksub(32)][row(65536)][8]; Sum z^2. NO LDS. ----
__global__ __launch_bounds__(256) void vq_cvt(
    const float* __restrict__ Z, u16* zah, float* __restrict__ sum) {
    const int t = threadIdx.x;
    const size_t rowbase = (size_t)blockIdx.x * 32;
    float ss = 0.0f;
    #pragma unroll
    for (int i = 0; i < 4; ++i) {
        int p = t + 256 * i;
        int row = p & 31, ks = p >> 5;   // lanes j, j+32 read adjacent 32B of one row
        const float4* src = (const float4*)(Z + (rowbase + row) * DDIM + ks * 8);
        float4 v0 = src[0], v1 = src[1];
        bf16x8 h8;
        h8[0] = (__bf16)v0.x; h8[1] = (__bf16)v0.y;
        h8[2] = (__bf16)v0.z; h8[3] = (__bf16)v0.w;
        h8[4] = (__bf16)v1.x; h8[5] = (__bf16)v1.y;
        h8[6] = (__bf16)v1.z; h8[7] = (__bf16)v1.w;
        ss += v0.x * v0.x + v0.y * v0.y + v0.z * v0.z + v0.w * v0.w
            + v1.x * v1.x + v1.y * v1.y + v1.z * v1.z + v1.w * v1.w;
        *(bf16x8*)(zah + ((size_t)ks * NROWS + rowbase + row) * 8) = h8;
    }
    // wave-reduce ss, one atomic per wave (loss term; any order OK)
    #pragma unroll
    for (int off = 1; off < 64; off <<= 1) ss += __shfl_xor(ss, off);
    if ((t & 63) == 0) atomicAdd(sum, ss);
}

// ---- tier-1 MFMA GEMM: LDS dbuf 64-code chunks, float top-2 fused ----
__device__ __forceinline__ void stage_chunk(
    const u16* __restrict__ ebh, int chbase, char* buf, int t) {
    // 64 codes x 32 ksubs x 16B; lane-linear LDS (p*16)
    #pragma unroll
    for (int i = 0; i < 8; ++i) {
        int p = t + 256 * i;
        int ks = p >> 6, c = p & 63;
        GLOAD_LDS16(ebh + ((size_t)ks * KCODES + chbase + c) * 8, buf + p * 16);
    }
}

__global__ __launch_bounds__(256, 2) void vq_gemm(
    const u16* zah,
    const u16* __restrict__ ebh,
    const float* __restrict__ ee,
    float* out, float* __restrict__ sum, int* __restrict__ count,
    int* __restrict__ list) {
    __shared__ __align__(16) char bs[2][32768];   // double-buffered B chunk
    const int t = threadIdx.x, w = t >> 6, l = t & 63;
    const int lr = l & 15, lg = l >> 4;
    const int rowbase = blockIdx.x * 128;

    // A fragments in registers: [rowfrag][kstep]
    bf16x8 aH[2][8];
    #pragma unroll
    for (int rf = 0; rf < 2; ++rf)
        #pragma unroll
        for (int s = 0; s < 8; ++s) {
            size_t off = ((size_t)(s * 4 + lg) * NROWS + rowbase + w * 32 + rf * 16 + lr) * 8;
            aH[rf][s] = *(const bf16x8*)(zah + off);
        }

    float s1[2][4], s2[2][4]; int i1[2][4];
    #pragma unroll
    for (int rf = 0; rf < 2; ++rf)
        #pragma unroll
        for (int r = 0; r < 4; ++r) { s1[rf][r] = 1e30f; s2[rf][r] = 1e30f; i1[rf][r] = 0x7FFFFFFF; }

    int cur = 0;
    stage_chunk(ebh, 0, bs[0], t);
    for (int ch = 0; ch < 16; ++ch) {
        __syncthreads();                    // drains this chunk's gload_lds
        if (ch + 1 < 16) stage_chunk(ebh, (ch + 1) * 64, bs[cur ^ 1], t);
        const char* buf = bs[cur];
        const int chbase = ch * 64;

        f32x4 acc[2][4];
        #pragma unroll
        for (int rf = 0; rf < 2; ++rf)
            #pragma unroll
            for (int cf = 0; cf < 4; ++cf) acc[rf][cf] = 0.0f;

        #pragma unroll
        for (int s = 0; s < 8; ++s) {
            #pragma unroll
            for (int cf = 0; cf < 4; ++cf) {
                int off = (((s * 4 + lg) * 64 + cf * 16 + lr) * 16);
                bf16x8 bh = *(const bf16x8*)(buf + off);
                #pragma unroll
                for (int rf = 0; rf < 2; ++rf)
                    acc[rf][cf] = __builtin_amdgcn_mfma_f32_16x16x32_bf16(aH[rf][s], bh, acc[rf][cf], 0, 0, 0);
            }
        }
        // epilogue: float top-2 (s2 via min/max median trick), codes ascending
        #pragma unroll
        for (int cf = 0; cf < 4; ++cf) {
            int code = chbase + cf * 16 + lr;
            float e2c = ee[code];
            #pragma unroll
            for (int rf = 0; rf < 2; ++rf)
                #pragma unroll
                for (int r = 0; r < 4; ++r) {
                    float v = __fmaf_rn(-2.0f, acc[rf][cf][r], e2c);
                    float so = s1[rf][r];
                    s2[rf][r] = fminf(fmaxf(so, v), s2[rf][r]);  // median(so,s2,v)
                    bool lt = v < so;
                    s1[rf][r] = lt ? v : so;
                    i1[rf][r] = lt ? code : i1[rf][r];
                }
        }
        cur ^= 1;
    }
    // butterfly across the 16 lanes of each row group (lr bits only)
    #pragma unroll
    for (int off = 1; off < 16; off <<= 1) {
        #pragma unroll
        for (int rf = 0; rf < 2; ++rf)
            #pragma unroll
            for (int r = 0; r < 4; ++r) {
                float os1 = __shfl_xor(s1[rf][r], off);
                float os2 = __shfl_xor(s2[rf][r], off);
                int   oi  = __shfl_xor(i1[rf][r], off);
                float ns2 = fminf(fmaxf(s1[rf][r], os1), fminf(s2[rf][r], os2));
                bool take = (os1 < s1[rf][r]) || (os1 == s1[rf][r] && oi < i1[rf][r]);
                s1[rf][r] = take ? os1 : s1[rf][r];
                i1[rf][r] = take ? oi : i1[rf][r];
                s2[rf][r] = ns2;
            }
    }
    if (lr == 0) {
        float lsum = 0.0f;
        #pragma unroll
        for (int rf = 0; rf < 2; ++rf)
            #pragma unroll
            for (int r = 0; r < 4; ++r) {
                int row = rowbase + w * 32 + rf * 16 + lg * 4 + r;
                out[(size_t)IDX_OFF + row] = (float)i1[rf][r];
                lsum += s1[rf][r];
                if (s2[rf][r] <= s1[rf][r] + MARGIN) {
                    int slot = atomicAdd(count, 1);
                    if (slot < RCAP) list[slot] = row;
                }
            }
        atomicAdd(sum, lsum);
    }
}

// ---- tier-2 exact np re-scan, BATCHED 16 rows/block (R6/R8 arithmetic) ----
__global__ __launch_bounds__(256) void vq_rescue(
    const float* __restrict__ Z, const float* __restrict__ E,
    const float* __restrict__ ee, const int* __restrict__ count,
    const int* __restrict__ list, float* out) {
    __shared__ float zrow[RBATCH][DDIM];    // 16 KB
    __shared__ float zacc[RBATCH][16];
    __shared__ float z2s[RBATCH];
    __shared__ u64 rmin[RBATCH];
    __shared__ int rowid[RBATCH];
    int n = *count; if (n > RCAP) n = RCAP;
    const int t = threadIdx.x;
    const int base = blockIdx.x * RBATCH;
    if (base >= n) return;
    int nb = n - base; if (nb > RBATCH) nb = RBATCH;

    if (t < RBATCH) {
        rowid[t] = (t < nb) ? list[base + t] : 0;
        rmin[t] = ~0ULL;
    }
    __syncthreads();
    // stage z rows (coalesced float4): 16 rows x 64 float4
    #pragma unroll
    for (int i = 0; i < RBATCH * (DDIM / 4) / 256; ++i) {
        int p = t + 256 * i;
        int r = p >> 6, c4 = p & 63;
        if (r < nb) ((float4*)zrow[r])[c4] =
            ((const float4*)(Z + (size_t)rowid[r] * DDIM))[c4];
    }
    __syncthreads();
    // np pairwise z2 per row
    if (t < RBATCH * 8) {
        int r = t >> 3, j = t & 7;
        const float* zr = zrow[r];
        float a0 = zr[j] * zr[j], a1 = zr[128 + j] * zr[128 + j];
        for (int i = 8; i < 128; i += 8) {
            a0 += zr[i + j] * zr[i + j];
            a1 += zr[128 + i + j] * zr[128 + i + j];
        }
        zacc[r][j] = a0; zacc[r][8 + j] = a1;
    }
    __syncthreads();
    if (t < RBATCH) {
        const float* a = zacc[t];
        float c0 = ((a[0] + a[1]) + (a[2] + a[3])) + ((a[4] + a[5]) + (a[6] + a[7]));
        float c1 = ((a[8] + a[9]) + (a[10] + a[11])) + ((a[12] + a[13]) + (a[14] + a[15]));
        z2s[t] = c0 + c1;
    }
    __syncthreads();

    // dots: thread t owns codes {t,+256,+512,+768} x all RBATCH rows;
    // strict sequential fp32 FMA chain over k ascending per (row,code).
    float acc[4][RBATCH];
    #pragma unroll
    for (int c = 0; c < 4; ++c)
        #pragma unroll
        for (int r = 0; r < RBATCH; ++r) acc[c][r] = 0.0f;

    for (int d4 = 0; d4 < DDIM / 4; ++d4) {
        float4 ev[4];
        #pragma unroll
        for (int c = 0; c < 4; ++c)
            ev[c] = ((const float4*)(E + (size_t)(t + c * 256) * DDIM))[d4];
        #pragma unroll
        for (int r = 0; r < RBATCH; ++r) {
            float4 zv = ((const float4*)zrow[r])[d4];
            #pragma unroll
            for (int c = 0; c < 4; ++c) {
                float a = acc[c][r];
                a = __fmaf_rn(zv.x, ev[c].x, a); a = __fmaf_rn(zv.y, ev[c].y, a);
                a = __fmaf_rn(zv.z, ev[c].z, a); a = __fmaf_rn(zv.w, ev[c].w, a);
                acc[c][r] = a;
            }
        }
    }
    // per-row argmin: np full-magnitude combine + first-min tie-break
    float e2c[4];
    #pragma unroll
    for (int c = 0; c < 4; ++c) e2c[c] = ee[t + c * 256];
    #pragma unroll
    for (int r = 0; r < RBATCH; ++r) {
        float zr2 = z2s[r];
        u64 best = ~0ULL;
        #pragma unroll
        for (int c = 0; c < 4; ++c) {
            float d = (zr2 + e2c[c]) - 2.0f * acc[c][r];
            u64 k = pack_key(d, (u32)(t + c * 256));
            if (k < best) best = k;
        }
        #pragma unroll
        for (int off = 1; off < 64; off <<= 1) {
            u64 o = __shfl_xor(best, off);
            if (o < best) best = o;
        }
        if ((t & 63) == 0) atomicMin(&rmin[r], best);
    }
    __syncthreads();
    if (t < nb) out[(size_t)IDX_OFF + rowid[t]] = (float)(u32)(rmin[t] & 0xFFFFFFFFu);
}

// ---- gather codebook rows into quantized output; block 0 writes loss ----
__global__ __launch_bounds__(256) void vq_qwrite(
    const float* __restrict__ E, const float* __restrict__ sum, float* out) {
    __shared__ int qidx[32];
    const int t = threadIdx.x;
    const size_t rowbase = (size_t)blockIdx.x * 32;
    if (blockIdx.x == 0 && t == 0) out[LOSS_OFF] = 1.25f * (*sum) / (float)QSIZE;
    if (t < 32) qidx[t] = (int)out[(size_t)IDX_OFF + rowbase + t];
    __syncthreads();
    float4* outq = (float4*)out;
    #pragma unroll
    for (int k = 0; k < 8; ++k) {
        int idx = t + 256 * k;
        int r = idx >> 6, c4 = idx & 63;
        int code = qidx[r];
        outq[rowbase * 64 + idx] = ((const float4*)(E + (size_t)code * DDIM))[c4];
    }
}

extern "C" void kernel_launch(void* const* d_in, const int* in_sizes, int n_in,
                              void* d_out, int out_size, void* d_ws, size_t ws_size,
                              hipStream_t stream) {
    const float* Z; const float* E;
    if (in_sizes[0] == QSIZE) { Z = (const float*)d_in[0]; E = (const float*)d_in[1]; }
    else                      { Z = (const float*)d_in[1]; E = (const float*)d_in[0]; }
    float* out = (float*)d_out;
    char* ws = (char*)d_ws;

    float* sum   = (float*)ws;                      // @0
    int*   count = (int*)(ws + 4);                  // @4
    float* ee    = (float*)(ws + 1024);             // 4 KB
    u16*   ebh   = (u16*)(ws + 8192);               // 512 KB
    int*   list  = (int*)(ws + 8192 + 524288);      // 64 KB (total ~0.6 MB)

    // bf16 z scratch lives in the q-output region until vq_qwrite
    u16* zah = (u16*)out;

    vq_pack_cb<<<4, 256, 0, stream>>>(E, ebh, ee, sum, count);
    vq_cvt<<<NROWS / 32, 256, 0, stream>>>(Z, zah, sum);
    vq_gemm<<<NROWS / 128, 256, 0, stream>>>(zah, ebh, ee, out, sum, count, list);
    vq_rescue<<<RCAP / RBATCH, 256, 0, stream>>>(Z, E, ee, count, list, out);
    vq_qwrite<<<NROWS / 32, 256, 0, stream>>>(E, sum, out);
}

// Round 15
// 231.609 us; speedup vs baseline: 3.5338x; 1.4502x over previous
//
#include <hip/hip_runtime.h>

// Disable implicit FP contraction: pairwise e^2/z^2 sums must round each
// product individually (numpy semantics). Explicit __fmaf_rn still fuses.
#pragma clang fp contract(off)

// VQ-VAE VectorQuantizer, two-tier:
//  Tier 1 (vq_gemm): plain-bf16 MFMA -> approx scores (err ~3e-5, same
//    order as np's own fp32 quantization). A-tile loaded DIRECTLY from Z
//    (fp32) and converted to bf16 fragments in registers (R14 lesson: the
//    separate cvt kernel + k-major scratch write was a 110us fixed cost at
//    ~600 GB/s). Sum(z^2) loss partial computed from the same registers.
//    Float top-2 via min/median, codes ascending = np first-occurrence.
//    Rows with top-2 gap <= MARGIN appended to list. B staged to LDS dbuf,
//    64-code chunks, 1 barrier/chunk.
//  Tier 2 (vq_rescue): EXACT np re-scan (R6-proven sequential-k fp32 FMA +
//    pairwise z2 + full-magnitude combine), BATCHED 16 rows/block.
//  Loss: 1.25*(sum(z^2) + sum(approx min score))/N  [2% threshold].
// Out (f32): [0..16777215] quantized_st, [16777216] loss, [16777217..] idx.

#define NROWS   65536
#define DDIM    256
#define KCODES  1024
#define QSIZE   (NROWS * DDIM)
#define LOSS_OFF QSIZE
#define IDX_OFF (QSIZE + 1)
#define MARGIN  3.0e-4f
#define RCAP    16384
#define RBATCH  16

typedef __bf16 bf16x8 __attribute__((ext_vector_type(8)));
typedef float f32x4 __attribute__((ext_vector_type(4)));
typedef unsigned int u32;
typedef unsigned long long u64;
typedef unsigned short u16;

#define GLOAD_LDS16(gsrc, ldst) \
    __builtin_amdgcn_global_load_lds( \
        (const __attribute__((address_space(1))) u32*)(gsrc), \
        (__attribute__((address_space(3))) u32*)(ldst), 16, 0, 0)

__device__ __forceinline__ u32 omap(float s) {
    u32 u = __float_as_uint(s);
    return (u & 0x80000000u) ? ~u : (u | 0x80000000u);
}
__device__ __forceinline__ u64 pack_key(float s, u32 j) {
    return ((u64)omap(s) << 32) | j;
}

// numpy pairwise sum-of-squares over 128 floats (unrolled-8 path)
__device__ __forceinline__ float pw128_sq(const float* __restrict__ x) {
    float r[8];
    #pragma unroll
    for (int j = 0; j < 8; ++j) r[j] = x[j] * x[j];
    for (int i = 8; i < 128; i += 8)
        #pragma unroll
        for (int j = 0; j < 8; ++j) r[j] += x[i + j] * x[i + j];
    return ((r[0] + r[1]) + (r[2] + r[3])) + ((r[4] + r[5]) + (r[6] + r[7]));
}

// ---- codebook prep: ebh bf16 [ksub(32)][code(1024)][8], np-e2 ----
__global__ __launch_bounds__(256) void vq_pack_cb(
    const float* __restrict__ E, u16* __restrict__ ebh,
    float* __restrict__ ee, float* __restrict__ sum, int* __restrict__ count) {
    int j = blockIdx.x * 256 + threadIdx.x;
    if (j == 0) { *sum = 0.0f; *count = 0; }
    if (j >= KCODES) return;
    const float* row = E + (size_t)j * DDIM;
    #pragma unroll
    for (int ks = 0; ks < 32; ++ks) {
        bf16x8 h8;
        #pragma unroll
        for (int e = 0; e < 8; ++e) h8[e] = (__bf16)row[ks * 8 + e];
        *(bf16x8*)(ebh + ((size_t)ks * KCODES + j) * 8) = h8;
    }
    ee[j] = pw128_sq(row) + pw128_sq(row + 128);
}

// ---- tier-1 MFMA GEMM: A direct from Z (fp32->bf16 in regs), B via LDS
//      dbuf 64-code chunks, float top-2 fused, loss partials fused ----
__device__ __forceinline__ void stage_chunk(
    const u16* __restrict__ ebh, int chbase, char* buf, int t) {
    // 64 codes x 32 ksubs x 16B; lane-linear LDS (p*16)
    #pragma unroll
    for (int i = 0; i < 8; ++i) {
        int p = t + 256 * i;
        int ks = p >> 6, c = p & 63;
        GLOAD_LDS16(ebh + ((size_t)ks * KCODES + chbase + c) * 8, buf + p * 16);
    }
}

__global__ __launch_bounds__(256, 2) void vq_gemm(
    const float* __restrict__ Z,
    const u16* __restrict__ ebh,
    const float* __restrict__ ee,
    float* out, float* __restrict__ sum, int* __restrict__ count,
    int* __restrict__ list) {
    __shared__ __align__(16) char bs[2][32768];   // double-buffered B chunk
    const int t = threadIdx.x, w = t >> 6, l = t & 63;
    const int lr = l & 15, lg = l >> 4;
    const int rowbase = blockIdx.x * 128;

    // A fragments: load fp32 from Z, convert to bf16 in regs.
    // aH[rf][s][e] = (bf16) Z[rowbase + w*32 + rf*16 + lr][(s*4+lg)*8 + e]
    // One (rf,s) load instruction: 16 rows x 128B contiguous segments.
    bf16x8 aH[2][8];
    float ss = 0.0f;                               // Sum z^2 partial (loss)
    #pragma unroll
    for (int rf = 0; rf < 2; ++rf) {
        const float* zr = Z + (size_t)(rowbase + w * 32 + rf * 16 + lr) * DDIM;
        #pragma unroll
        for (int s = 0; s < 8; ++s) {
            const float4* src = (const float4*)(zr + (s * 4 + lg) * 8);
            float4 v0 = src[0], v1 = src[1];
            bf16x8 h8;
            h8[0] = (__bf16)v0.x; h8[1] = (__bf16)v0.y;
            h8[2] = (__bf16)v0.z; h8[3] = (__bf16)v0.w;
            h8[4] = (__bf16)v1.x; h8[5] = (__bf16)v1.y;
            h8[6] = (__bf16)v1.z; h8[7] = (__bf16)v1.w;
            aH[rf][s] = h8;
            ss += v0.x * v0.x + v0.y * v0.y + v0.z * v0.z + v0.w * v0.w
                + v1.x * v1.x + v1.y * v1.y + v1.z * v1.z + v1.w * v1.w;
        }
    }
    // wave-reduce ss, one atomic per wave (any order OK for loss)
    #pragma unroll
    for (int off = 1; off < 64; off <<= 1) ss += __shfl_xor(ss, off);
    if (l == 0) atomicAdd(sum, ss);

    float s1[2][4], s2[2][4]; int i1[2][4];
    #pragma unroll
    for (int rf = 0; rf < 2; ++rf)
        #pragma unroll
        for (int r = 0; r < 4; ++r) { s1[rf][r] = 1e30f; s2[rf][r] = 1e30f; i1[rf][r] = 0x7FFFFFFF; }

    int cur = 0;
    stage_chunk(ebh, 0, bs[0], t);
    for (int ch = 0; ch < 16; ++ch) {
        __syncthreads();                    // drains this chunk's gload_lds
        if (ch + 1 < 16) stage_chunk(ebh, (ch + 1) * 64, bs[cur ^ 1], t);
        const char* buf = bs[cur];
        const int chbase = ch * 64;

        f32x4 acc[2][4];
        #pragma unroll
        for (int rf = 0; rf < 2; ++rf)
            #pragma unroll
            for (int cf = 0; cf < 4; ++cf) acc[rf][cf] = 0.0f;

        #pragma unroll
        for (int s = 0; s < 8; ++s) {
            #pragma unroll
            for (int cf = 0; cf < 4; ++cf) {
                int off = (((s * 4 + lg) * 64 + cf * 16 + lr) * 16);
                bf16x8 bh = *(const bf16x8*)(buf + off);
                #pragma unroll
                for (int rf = 0; rf < 2; ++rf)
                    acc[rf][cf] = __builtin_amdgcn_mfma_f32_16x16x32_bf16(aH[rf][s], bh, acc[rf][cf], 0, 0, 0);
            }
        }
        // epilogue: float top-2 (s2 via min/max median trick), codes ascending
        #pragma unroll
        for (int cf = 0; cf < 4; ++cf) {
            int code = chbase + cf * 16 + lr;
            float e2c = ee[code];
            #pragma unroll
            for (int rf = 0; rf < 2; ++rf)
                #pragma unroll
                for (int r = 0; r < 4; ++r) {
                    float v = __fmaf_rn(-2.0f, acc[rf][cf][r], e2c);
                    float so = s1[rf][r];
                    s2[rf][r] = fminf(fmaxf(so, v), s2[rf][r]);  // median(so,s2,v)
                    bool lt = v < so;
                    s1[rf][r] = lt ? v : so;
                    i1[rf][r] = lt ? code : i1[rf][r];
                }
        }
        cur ^= 1;
    }
    // butterfly across the 16 lanes of each row group (lr bits only)
    #pragma unroll
    for (int off = 1; off < 16; off <<= 1) {
        #pragma unroll
        for (int rf = 0; rf < 2; ++rf)
            #pragma unroll
            for (int r = 0; r < 4; ++r) {
                float os1 = __shfl_xor(s1[rf][r], off);
                float os2 = __shfl_xor(s2[rf][r], off);
                int   oi  = __shfl_xor(i1[rf][r], off);
                float ns2 = fminf(fmaxf(s1[rf][r], os1), fminf(s2[rf][r], os2));
                bool take = (os1 < s1[rf][r]) || (os1 == s1[rf][r] && oi < i1[rf][r]);
                s1[rf][r] = take ? os1 : s1[rf][r];
                i1[rf][r] = take ? oi : i1[rf][r];
                s2[rf][r] = ns2;
            }
    }
    if (lr == 0) {
        float lsum = 0.0f;
        #pragma unroll
        for (int rf = 0; rf < 2; ++rf)
            #pragma unroll
            for (int r = 0; r < 4; ++r) {
                int row = rowbase + w * 32 + rf * 16 + lg * 4 + r;
                out[(size_t)IDX_OFF + row] = (float)i1[rf][r];
                lsum += s1[rf][r];
                if (s2[rf][r] <= s1[rf][r] + MARGIN) {
                    int slot = atomicAdd(count, 1);
                    if (slot < RCAP) list[slot] = row;
                }
            }
        atomicAdd(sum, lsum);
    }
}

// ---- tier-2 exact np re-scan, BATCHED 16 rows/block (R6/R8 arithmetic) ----
__global__ __launch_bounds__(256) void vq_rescue(
    const float* __restrict__ Z, const float* __restrict__ E,
    const float* __restrict__ ee, const int* __restrict__ count,
    const int* __restrict__ list, float* out) {
    __shared__ float zrow[RBATCH][DDIM];    // 16 KB
    __shared__ float zacc[RBATCH][16];
    __shared__ float z2s[RBATCH];
    __shared__ u64 rmin[RBATCH];
    __shared__ int rowid[RBATCH];
    int n = *count; if (n > RCAP) n = RCAP;
    const int t = threadIdx.x;
    const int base = blockIdx.x * RBATCH;
    if (base >= n) return;
    int nb = n - base; if (nb > RBATCH) nb = RBATCH;

    if (t < RBATCH) {
        rowid[t] = (t < nb) ? list[base + t] : 0;
        rmin[t] = ~0ULL;
    }
    __syncthreads();
    // stage z rows (coalesced float4): 16 rows x 64 float4
    #pragma unroll
    for (int i = 0; i < RBATCH * (DDIM / 4) / 256; ++i) {
        int p = t + 256 * i;
        int r = p >> 6, c4 = p & 63;
        if (r < nb) ((float4*)zrow[r])[c4] =
            ((const float4*)(Z + (size_t)rowid[r] * DDIM))[c4];
    }
    __syncthreads();
    // np pairwise z2 per row
    if (t < RBATCH * 8) {
        int r = t >> 3, j = t & 7;
        const float* zr = zrow[r];
        float a0 = zr[j] * zr[j], a1 = zr[128 + j] * zr[128 + j];
        for (int i = 8; i < 128; i += 8) {
            a0 += zr[i + j] * zr[i + j];
            a1 += zr[128 + i + j] * zr[128 + i + j];
        }
        zacc[r][j] = a0; zacc[r][8 + j] = a1;
    }
    __syncthreads();
    if (t < RBATCH) {
        const float* a = zacc[t];
        float c0 = ((a[0] + a[1]) + (a[2] + a[3])) + ((a[4] + a[5]) + (a[6] + a[7]));
        float c1 = ((a[8] + a[9]) + (a[10] + a[11])) + ((a[12] + a[13]) + (a[14] + a[15]));
        z2s[t] = c0 + c1;
    }
    __syncthreads();

    // dots: thread t owns codes {t,+256,+512,+768} x all RBATCH rows;
    // strict sequential fp32 FMA chain over k ascending per (row,code).
    float acc[4][RBATCH];
    #pragma unroll
    for (int c = 0; c < 4; ++c)
        #pragma unroll
        for (int r = 0; r < RBATCH; ++r) acc[c][r] = 0.0f;

    for (int d4 = 0; d4 < DDIM / 4; ++d4) {
        float4 ev[4];
        #pragma unroll
        for (int c = 0; c < 4; ++c)
            ev[c] = ((const float4*)(E + (size_t)(t + c * 256) * DDIM))[d4];
        #pragma unroll
        for (int r = 0; r < RBATCH; ++r) {
            float4 zv = ((const float4*)zrow[r])[d4];
            #pragma unroll
            for (int c = 0; c < 4; ++c) {
                float a = acc[c][r];
                a = __fmaf_rn(zv.x, ev[c].x, a); a = __fmaf_rn(zv.y, ev[c].y, a);
                a = __fmaf_rn(zv.z, ev[c].z, a); a = __fmaf_rn(zv.w, ev[c].w, a);
                acc[c][r] = a;
            }
        }
    }
    // per-row argmin: np full-magnitude combine + first-min tie-break
    float e2c[4];
    #pragma unroll
    for (int c = 0; c < 4; ++c) e2c[c] = ee[t + c * 256];
    #pragma unroll
    for (int r = 0; r < RBATCH; ++r) {
        float zr2 = z2s[r];
        u64 best = ~0ULL;
        #pragma unroll
        for (int c = 0; c < 4; ++c) {
            float d = (zr2 + e2c[c]) - 2.0f * acc[c][r];
            u64 k = pack_key(d, (u32)(t + c * 256));
            if (k < best) best = k;
        }
        #pragma unroll
        for (int off = 1; off < 64; off <<= 1) {
            u64 o = __shfl_xor(best, off);
            if (o < best) best = o;
        }
        if ((t & 63) == 0) atomicMin(&rmin[r], best);
    }
    __syncthreads();
    if (t < nb) out[(size_t)IDX_OFF + rowid[t]] = (float)(u32)(rmin[t] & 0xFFFFFFFFu);
}

// ---- gather codebook rows into quantized output; block 0 writes loss ----
__global__ __launch_bounds__(256) void vq_qwrite(
    const float* __restrict__ E, const float* __restrict__ sum, float* out) {
    __shared__ int qidx[32];
    const int t = threadIdx.x;
    const size_t rowbase = (size_t)blockIdx.x * 32;
    if (blockIdx.x == 0 && t == 0) out[LOSS_OFF] = 1.25f * (*sum) / (float)QSIZE;
    if (t < 32) qidx[t] = (int)out[(size_t)IDX_OFF + rowbase + t];
    __syncthreads();
    float4* outq = (float4*)out;
    #pragma unroll
    for (int k = 0; k < 8; ++k) {
        int idx = t + 256 * k;
        int r = idx >> 6, c4 = idx & 63;
        int code = qidx[r];
        outq[rowbase * 64 + idx] = ((const float4*)(E + (size_t)code * DDIM))[c4];
    }
}

extern "C" void kernel_launch(void* const* d_in, const int* in_sizes, int n_in,
                              void* d_out, int out_size, void* d_ws, size_t ws_size,
                              hipStream_t stream) {
    const float* Z; const float* E;
    if (in_sizes[0] == QSIZE) { Z = (const float*)d_in[0]; E = (const float*)d_in[1]; }
    else                      { Z = (const float*)d_in[1]; E = (const float*)d_in[0]; }
    float* out = (float*)d_out;
    char* ws = (char*)d_ws;

    float* sum   = (float*)ws;                      // @0
    int*   count = (int*)(ws + 4);                  // @4
    float* ee    = (float*)(ws + 1024);             // 4 KB
    u16*   ebh   = (u16*)(ws + 8192);               // 512 KB
    int*   list  = (int*)(ws + 8192 + 524288);      // 64 KB (total ~0.6 MB)

    vq_pack_cb<<<4, 256, 0, stream>>>(E, ebh, ee, sum, count);
    vq_gemm<<<NROWS / 128, 256, 0, stream>>>(Z, ebh, ee, out, sum, count, list);
    vq_rescue<<<RCAP / RBATCH, 256, 0, stream>>>(Z, E, ee, count, list, out);
    vq_qwrite<<<NROWS / 32, 256, 0, stream>>>(E, sum, out);
}